// Round 3
// baseline (663.717 us; speedup 1.0000x reference)
//
#include <hip/hip_runtime.h>
#include <hip/hip_bf16.h>
#include <stdint.h>

// Problem constants
#define T_TOK 4096   // B*S
#define H_DIM 1024
#define F_DIM 2816
#define E_NUM 8
#define ROWS_CAP 9216   // 8192 + 8*128 padding headroom
#define TOTAL_MT 72     // ROWS_CAP / 128

typedef float  f32x4  __attribute__((ext_vector_type(4)));
typedef __bf16 bf16x8 __attribute__((ext_vector_type(8)));

__device__ __forceinline__ unsigned short f32_bf16(float f) {
  union { float f; unsigned u; } v; v.f = f;
  unsigned r = v.u + 0x7fffu + ((v.u >> 16) & 1u);
  return (unsigned short)(r >> 16);
}

__device__ __forceinline__ void async16(const void* g, void* l) {
  __builtin_amdgcn_global_load_lds(
      (__attribute__((address_space(1))) void*)(g),
      (__attribute__((address_space(3))) void*)(l),
      16, 0, 0);
}

__device__ __forceinline__ f32x4 mfma16(bf16x8 a, bf16x8 b, f32x4 c) {
  return __builtin_amdgcn_mfma_f32_16x16x32_bf16(a, b, c, 0, 0, 0);
}

// ---------------- converts ----------------

// x fp32 [T,H] -> bf16 [T,H]
__global__ __launch_bounds__(256) void conv_x_kernel(const float* __restrict__ x,
                                                     unsigned short* __restrict__ xb) {
  int i = blockIdx.x * 256 + threadIdx.x;   // one float4 per thread
  float4 v = ((const float4*)x)[i];
  ushort4 o;
  o.x = f32_bf16(v.x); o.y = f32_bf16(v.y); o.z = f32_bf16(v.z); o.w = f32_bf16(v.w);
  ((ushort4*)xb)[i] = o;
}

// Unified transpose+convert, FLAT grid: exactly 3*704 live 64x64 tiles.
// src [R][C] fp32 -> dst [C][R] bf16.
__global__ __launch_bounds__(256) void transpose_all(const float* __restrict__ wg,
                                                     const float* __restrict__ wu,
                                                     const float* __restrict__ wd,
                                                     unsigned short* __restrict__ Wgt,
                                                     unsigned short* __restrict__ Wut,
                                                     unsigned short* __restrict__ Wdt) {
  int bx = blockIdx.x;            // [0, 2112)
  int mz = bx / 704, local = bx % 704;
  const float* s; unsigned short* d; int R, C, tx;
  size_t mat = (size_t)H_DIM * F_DIM;
  if (mz == 0)      { s = wg; d = Wgt; R = H_DIM; C = F_DIM; tx = 44; }
  else if (mz == 1) { s = wu; d = Wut; R = H_DIM; C = F_DIM; tx = 44; }
  else              { s = wd; d = Wdt; R = F_DIM; C = H_DIM; tx = 16; }
  int c0 = (local % tx) * 64;
  int rg0 = (local / tx) * 64;
  int e = blockIdx.y;
  s += e * mat; d += e * mat;
  int r0 = rg0;

  __shared__ float tile[64 * 65];
  int tid = threadIdx.x;
  int rr = tid >> 4, c4 = tid & 15;
#pragma unroll
  for (int it = 0; it < 4; it++) {
    int r = rr + 16 * it;
    float4 v = *(const float4*)(s + (size_t)(r0 + r) * C + c0 + c4 * 4);
    tile[r * 65 + c4 * 4 + 0] = v.x;
    tile[r * 65 + c4 * 4 + 1] = v.y;
    tile[r * 65 + c4 * 4 + 2] = v.z;
    tile[r * 65 + c4 * 4 + 3] = v.w;
  }
  __syncthreads();
  int cc = tid >> 4, r4 = tid & 15;
#pragma unroll
  for (int it = 0; it < 4; it++) {
    int c = cc + 16 * it;
    ushort4 o;
    o.x = f32_bf16(tile[(r4 * 4 + 0) * 65 + c]);
    o.y = f32_bf16(tile[(r4 * 4 + 1) * 65 + c]);
    o.z = f32_bf16(tile[(r4 * 4 + 2) * 65 + c]);
    o.w = f32_bf16(tile[(r4 * 4 + 3) * 65 + c]);
    *(ushort4*)(d + (size_t)(c0 + c) * R + r0 + r4 * 4) = o;
  }
}

// ---------------- router ----------------

__global__ __launch_bounds__(256) void router_kernel(const float* __restrict__ x,
                                                     const float* __restrict__ rw,
                                                     int* __restrict__ t2i,
                                                     float* __restrict__ t2w,
                                                     int* __restrict__ counts,
                                                     float* __restrict__ psum) {
  __shared__ float srw[E_NUM * H_DIM];  // 32 KB
  __shared__ float sP[E_NUM];
  __shared__ int sC[E_NUM];
  int tid = threadIdx.x;
  for (int i = tid; i < E_NUM * H_DIM; i += 256) srw[i] = rw[i];
  if (tid < E_NUM) { sP[tid] = 0.f; sC[tid] = 0; }
  __syncthreads();
  int w = tid >> 6, lane = tid & 63;
  for (int it = 0; it < 4; ++it) {
    int t = blockIdx.x * 16 + w * 4 + it;
    float acc[E_NUM];
#pragma unroll
    for (int e = 0; e < E_NUM; e++) acc[e] = 0.f;
    const float* xr = x + (size_t)t * H_DIM;
    for (int h = lane; h < H_DIM; h += 64) {
      float xv = xr[h];
#pragma unroll
      for (int e = 0; e < E_NUM; e++) acc[e] += xv * srw[e * H_DIM + h];
    }
#pragma unroll
    for (int e = 0; e < E_NUM; e++) {
      float v = acc[e];
      for (int o = 32; o > 0; o >>= 1) v += __shfl_down(v, o, 64);
      acc[e] = __shfl(v, 0, 64);
    }
    if (lane == 0) {
      float mx = acc[0];
#pragma unroll
      for (int e = 1; e < E_NUM; e++) mx = fmaxf(mx, acc[e]);
      float pr[E_NUM], s = 0.f;
#pragma unroll
      for (int e = 0; e < E_NUM; e++) { pr[e] = __expf(acc[e] - mx); s += pr[e]; }
      float inv = 1.f / s;
#pragma unroll
      for (int e = 0; e < E_NUM; e++) atomicAdd(&sP[e], pr[e] * inv);
      int i0 = 0; float v0 = acc[0];
#pragma unroll
      for (int e = 1; e < E_NUM; e++) if (acc[e] > v0) { v0 = acc[e]; i0 = e; }
      int i1 = -1; float v1 = -3.4e38f;
#pragma unroll
      for (int e = 0; e < E_NUM; e++) if (e != i0 && acc[e] > v1) { v1 = acc[e]; i1 = e; }
      float e1 = __expf(v1 - v0);
      float w0 = 1.f / (1.f + e1);
      t2i[2 * t] = i0; t2i[2 * t + 1] = i1;
      t2w[2 * t] = w0; t2w[2 * t + 1] = e1 * w0;
      atomicAdd(&sC[i0], 1); atomicAdd(&sC[i1], 1);
    }
  }
  __syncthreads();
  if (tid < E_NUM) { atomicAdd(&counts[tid], sC[tid]); atomicAdd(&psum[tid], sP[tid]); }
}

__global__ void scan_aux_kernel(const int* __restrict__ counts, const float* __restrict__ psum,
                                int* __restrict__ offsets, int* __restrict__ cursors,
                                float* __restrict__ aux_out) {
  if (threadIdx.x == 0 && blockIdx.x == 0) {
    int off = 0; float aux = 0.f;
    for (int e = 0; e < E_NUM; e++) {
      offsets[e] = off;
      cursors[e] = off;
      off += (counts[e] + 127) & ~127;
      aux += ((float)counts[e] / 8192.0f) * (psum[e] / 4096.0f);
    }
    offsets[E_NUM] = off;
    *aux_out = 8.0f * aux;
  }
}

__global__ __launch_bounds__(256) void assign_kernel(const int* __restrict__ t2i,
                                                     const float* __restrict__ t2w,
                                                     int* __restrict__ cursors,
                                                     int* __restrict__ row2token,
                                                     float* __restrict__ roww,
                                                     int* __restrict__ t2row) {
  int t = blockIdx.x * 256 + threadIdx.x;
#pragma unroll
  for (int s = 0; s < 2; s++) {
    int e = t2i[2 * t + s];
    int p = atomicAdd(&cursors[e], 1);
    row2token[p] = t;
    roww[p] = t2w[2 * t + s];
    t2row[2 * t + s] = p;
  }
}

// Map a global (padded) row-tile index to its expert via offsets[].
__device__ __forceinline__ int find_expert(const int* __restrict__ offsets, int row0,
                                           int& off_out) {
  int esel = -1, off = 0;
#pragma unroll
  for (int e = 0; e < E_NUM; e++) {
    int lo = offsets[e], hi = offsets[e + 1];
    if (row0 >= lo && row0 < hi) { esel = e; off = lo; }
  }
  off_out = off;
  return esel;
}

// ---------------- fused gate/up GEMM ----------------
// act[row, f] = silu(x@Wg) * (x@Wu), bf16.  BM=128, BN=64, BK=32.
// Round-3: 4-deep LDS pipeline (prefetch 3 ahead, steady vmcnt(12), never
// drain to 0 in-loop) + T2 XOR chunk swizzle (bank-conflict-free, verified
// round-2: SQ_LDS_BANK_CONFLICT 1.2e7 -> 0).
// Race proof: iter t writes slot (t+3)&3 == (t-1)&3; all readers of that
// slot passed the trailing barrier of iter t-1.  Per-wave vmcnt(12) drains
// its own stage-t loads before the leading barrier -> buffer t visible to
// all waves post-barrier.
__global__ __launch_bounds__(256) void gateup_kernel(
    const unsigned short* __restrict__ xb,
    const unsigned short* __restrict__ wgt,
    const unsigned short* __restrict__ wut,
    unsigned short* __restrict__ act,
    const int* __restrict__ counts, const int* __restrict__ offsets,
    const int* __restrict__ row2token) {
  int g = blockIdx.x;
  int row0 = g * 128;
  int off;
  int e = find_expert(offsets, row0, off);
  if (e < 0) return;
  int cnt = counts[e];
  int rowbase = row0 - off;
  int ntile = blockIdx.y;     // F/64 = 44

  __shared__ __align__(16) unsigned short smA[4][128 * 32];  // 32 KB
  __shared__ __align__(16) unsigned short smG[4][64 * 32];   // 16 KB
  __shared__ __align__(16) unsigned short smU[4][64 * 32];   // 16 KB

  int tid = threadIdx.x;
  int w = tid >> 6, lane = tid & 63;
  int wm = w & 1, wn = w >> 1;  // wave tile 64x32 within 128x64

  // staging: thread tid owns dest (row=tid>>2, chunk=tid&3); source chunk
  // pre-swizzled so that a swizzled ds_read recovers the logical layout.
  int rA0 = tid >> 2, qA0 = tid & 3;
  int qs = qA0 ^ ((rA0 >> 1) & 3);
  int rA1 = rA0 + 64;   // (rA1>>1)&3 == (rA0>>1)&3, same swizzle
  int tok0 = (rowbase + rA0 < cnt) ? row2token[off + rowbase + rA0] : 0;
  int tok1 = (rowbase + rA1 < cnt) ? row2token[off + rowbase + rA1] : 0;
  const unsigned short* gA0 = xb + (size_t)tok0 * H_DIM + qs * 8;
  const unsigned short* gA1 = xb + (size_t)tok1 * H_DIM + qs * 8;
  size_t wb = (size_t)e * F_DIM * H_DIM;
  const unsigned short* gG = wgt + wb + (size_t)(ntile * 64 + rA0) * H_DIM + qs * 8;
  const unsigned short* gU = wut + wb + (size_t)(ntile * 64 + rA0) * H_DIM + qs * 8;
  unsigned short* lA0 = &smA[0][0] + (w * 64) * 8;
  unsigned short* lA1 = &smA[0][0] + (256 + w * 64) * 8;
  unsigned short* lG = &smG[0][0] + (w * 64) * 8;
  unsigned short* lU = &smU[0][0] + (w * 64) * 8;

  f32x4 accg[4][2], accu[4][2];
#pragma unroll
  for (int i = 0; i < 4; i++)
#pragma unroll
    for (int j = 0; j < 2; j++) {
      accg[i][j] = (f32x4){0.f, 0.f, 0.f, 0.f};
      accu[i][j] = (f32x4){0.f, 0.f, 0.f, 0.f};
    }

  int m = lane & 15, quad = lane >> 4;
  // read-side swizzled chunk offset (ushorts); per-thread constant.
  int co = (quad ^ ((m >> 1) & 3)) * 8;

#define GU_STAGE(buf, k0)                                      \
  do {                                                         \
    async16(gA0 + (k0), lA0 + (buf) * (128 * 32));             \
    async16(gA1 + (k0), lA1 + (buf) * (128 * 32));             \
    async16(gG + (k0), lG + (buf) * (64 * 32));                \
    async16(gU + (k0), lU + (buf) * (64 * 32));                \
  } while (0)

  GU_STAGE(0, 0);
  GU_STAGE(1, 32);
  GU_STAGE(2, 64);
  for (int t = 0; t < 32; ++t) {
    if (t < 29) {
      GU_STAGE((t + 3) & 3, (t + 3) * 32);
      asm volatile("s_waitcnt vmcnt(12)" ::: "memory");  // stage t drained
    } else if (t == 29) {
      asm volatile("s_waitcnt vmcnt(8)" ::: "memory");
    } else if (t == 30) {
      asm volatile("s_waitcnt vmcnt(4)" ::: "memory");
    } else {
      asm volatile("s_waitcnt vmcnt(0)" ::: "memory");
    }
    __builtin_amdgcn_s_barrier();
    int cb = t & 3;
    const unsigned short* bA = &smA[0][0] + cb * (128 * 32);
    const unsigned short* bG = &smG[0][0] + cb * (64 * 32);
    const unsigned short* bU = &smU[0][0] + cb * (64 * 32);
    bf16x8 a[4], bg[2], bu[2];
#pragma unroll
    for (int i = 0; i < 4; i++)
      a[i] = *(const bf16x8*)(bA + (wm * 64 + 16 * i + m) * 32 + co);
#pragma unroll
    for (int j = 0; j < 2; j++) {
      bg[j] = *(const bf16x8*)(bG + (wn * 32 + 16 * j + m) * 32 + co);
      bu[j] = *(const bf16x8*)(bU + (wn * 32 + 16 * j + m) * 32 + co);
    }
#pragma unroll
    for (int i = 0; i < 4; i++)
#pragma unroll
      for (int j = 0; j < 2; j++) {
        accg[i][j] = mfma16(a[i], bg[j], accg[i][j]);
        accu[i][j] = mfma16(a[i], bu[j], accu[i][j]);
      }
    __builtin_amdgcn_s_barrier();  // readers done before slot reuse next iter
  }
#undef GU_STAGE

#pragma unroll
  for (int i = 0; i < 4; i++)
#pragma unroll
    for (int j = 0; j < 2; j++)
#pragma unroll
      for (int r = 0; r < 4; r++) {
        int rt = wm * 64 + 16 * i + quad * 4 + r;
        int ct = wn * 32 + 16 * j + m;
        float g2 = accg[i][j][r], u = accu[i][j][r];
        float sv = g2 / (1.f + __expf(-g2)) * u;
        act[(size_t)(off + rowbase + rt) * F_DIM + ntile * 64 + ct] = f32_bf16(sv);
      }
}

// ---------------- down GEMM, split-k x2 -> Y scratch ----------------
// Y[ks][row, h] = w_row * (act[:, ks*1408:+1408] @ Wd[ks*1408:+1408, :]).
// Same 4-deep pipeline + swizzle as gateup.
__global__ __launch_bounds__(256) void down_kernel(
    const unsigned short* __restrict__ act,
    const unsigned short* __restrict__ wdt,   // [E][H][F] k-contig
    const int* __restrict__ counts, const int* __restrict__ offsets,
    const float* __restrict__ roww,
    float* __restrict__ Y) {
  int g = blockIdx.x;
  int row0 = g * 128;
  int off;
  int e = find_expert(offsets, row0, off);
  if (e < 0) return;
  int cnt = counts[e];
  int rowbase = row0 - off;
  int ntile = blockIdx.y;  // H/128 = 8
  int ks = blockIdx.z;     // split-k slice
  int kbase = ks * (F_DIM / 2);

  __shared__ __align__(16) unsigned short smA[4][128 * 32];  // 32 KB
  __shared__ __align__(16) unsigned short smB[4][128 * 32];  // 32 KB

  int tid = threadIdx.x;
  int w = tid >> 6, lane = tid & 63;
  int wm = w & 1, wn = w >> 1;  // wave tile 64x64

  int r0 = tid >> 2, q0 = tid & 3;
  int qs = q0 ^ ((r0 >> 1) & 3);
  int r1 = r0 + 64;
  const unsigned short* gA0 = act + (size_t)(off + rowbase + r0) * F_DIM + kbase + qs * 8;
  const unsigned short* gA1 = act + (size_t)(off + rowbase + r1) * F_DIM + kbase + qs * 8;
  size_t wb = (size_t)e * H_DIM * F_DIM;
  const unsigned short* gB0 = wdt + wb + (size_t)(ntile * 128 + r0) * F_DIM + kbase + qs * 8;
  const unsigned short* gB1 = wdt + wb + (size_t)(ntile * 128 + r1) * F_DIM + kbase + qs * 8;
  unsigned short* lA0 = &smA[0][0] + tid * 8;
  unsigned short* lA1 = &smA[0][0] + (tid + 256) * 8;
  unsigned short* lB0 = &smB[0][0] + tid * 8;
  unsigned short* lB1 = &smB[0][0] + (tid + 256) * 8;

  f32x4 acc[4][4];
#pragma unroll
  for (int i = 0; i < 4; i++)
#pragma unroll
    for (int j = 0; j < 4; j++) acc[i][j] = (f32x4){0.f, 0.f, 0.f, 0.f};

  int m = lane & 15, quad = lane >> 4;
  int co = (quad ^ ((m >> 1) & 3)) * 8;

#define DN_STAGE(buf, k0)                                      \
  do {                                                         \
    async16(gA0 + (k0), lA0 + (buf) * (128 * 32));             \
    async16(gA1 + (k0), lA1 + (buf) * (128 * 32));             \
    async16(gB0 + (k0), lB0 + (buf) * (128 * 32));             \
    async16(gB1 + (k0), lB1 + (buf) * (128 * 32));             \
  } while (0)

  DN_STAGE(0, 0);
  DN_STAGE(1, 32);
  DN_STAGE(2, 64);
  for (int t = 0; t < 44; ++t) {   // (F_DIM/2)/32
    if (t < 41) {
      DN_STAGE((t + 3) & 3, (t + 3) * 32);
      asm volatile("s_waitcnt vmcnt(12)" ::: "memory");
    } else if (t == 41) {
      asm volatile("s_waitcnt vmcnt(8)" ::: "memory");
    } else if (t == 42) {
      asm volatile("s_waitcnt vmcnt(4)" ::: "memory");
    } else {
      asm volatile("s_waitcnt vmcnt(0)" ::: "memory");
    }
    __builtin_amdgcn_s_barrier();
    int cb = t & 3;
    const unsigned short* bA = &smA[0][0] + cb * (128 * 32);
    const unsigned short* bB = &smB[0][0] + cb * (128 * 32);
    bf16x8 a[4], b[4];
#pragma unroll
    for (int i = 0; i < 4; i++) {
      a[i] = *(const bf16x8*)(bA + (wm * 64 + 16 * i + m) * 32 + co);
      b[i] = *(const bf16x8*)(bB + (wn * 64 + 16 * i + m) * 32 + co);
    }
#pragma unroll
    for (int i = 0; i < 4; i++)
#pragma unroll
      for (int j = 0; j < 4; j++) acc[i][j] = mfma16(a[i], b[j], acc[i][j]);
    __builtin_amdgcn_s_barrier();
  }
#undef DN_STAGE

  float* Yk = Y + (size_t)ks * ROWS_CAP * H_DIM;
#pragma unroll
  for (int i = 0; i < 4; i++)
#pragma unroll
    for (int r = 0; r < 4; r++) {
      int rt = wm * 64 + 16 * i + quad * 4 + r;
      int lrow = rowbase + rt;
      if (lrow < cnt) {
        float cw = roww[off + lrow];
#pragma unroll
        for (int j = 0; j < 4; j++) {
          int h = ntile * 128 + wn * 64 + 16 * j + m;
          Yk[(size_t)(off + lrow) * H_DIM + h] = cw * acc[i][j][r];
        }
      }
    }
}

// out[t] = sum over 2 rows x 2 k-slices of Y
__global__ __launch_bounds__(256) void combine_kernel(const float* __restrict__ Y,
                                                      const int* __restrict__ t2row,
                                                      float* __restrict__ out) {
  int t = blockIdx.x, hc = threadIdx.x;
  int r0 = t2row[2 * t], r1 = t2row[2 * t + 1];
  const float* Y1 = Y + (size_t)ROWS_CAP * H_DIM;
  float4 a = ((const float4*)(Y  + (size_t)r0 * H_DIM))[hc];
  float4 b = ((const float4*)(Y  + (size_t)r1 * H_DIM))[hc];
  float4 c = ((const float4*)(Y1 + (size_t)r0 * H_DIM))[hc];
  float4 d = ((const float4*)(Y1 + (size_t)r1 * H_DIM))[hc];
  float4 o;
  o.x = (a.x + b.x) + (c.x + d.x);
  o.y = (a.y + b.y) + (c.y + d.y);
  o.z = (a.z + b.z) + (c.z + d.z);
  o.w = (a.w + b.w) + (c.w + d.w);
  ((float4*)(out + (size_t)t * H_DIM))[hc] = o;
}

// ---------------- host ----------------

extern "C" void kernel_launch(void* const* d_in, const int* in_sizes, int n_in,
                              void* d_out, int out_size, void* d_ws, size_t ws_size,
                              hipStream_t stream) {
  const float* x  = (const float*)d_in[0];
  const float* rw = (const float*)d_in[1];
  const float* wg = (const float*)d_in[2];
  const float* wu = (const float*)d_in[3];
  const float* wd = (const float*)d_in[4];
  float* out = (float*)d_out;

  char* ws = (char*)d_ws;
  size_t p = 0;
  auto alloc = [&](size_t bytes) {
    char* r = ws + p;
    p = (p + bytes + 255) & ~(size_t)255;
    return r;
  };
  unsigned short* Xb  = (unsigned short*)alloc((size_t)T_TOK * H_DIM * 2);
  unsigned short* Wgt = (unsigned short*)alloc((size_t)E_NUM * F_DIM * H_DIM * 2);
  unsigned short* Wut = (unsigned short*)alloc((size_t)E_NUM * F_DIM * H_DIM * 2);
  unsigned short* Wdt = (unsigned short*)alloc((size_t)E_NUM * H_DIM * F_DIM * 2);
  unsigned short* Act = (unsigned short*)alloc((size_t)ROWS_CAP * F_DIM * 2);
  int*   t2i = (int*)alloc(T_TOK * 2 * 4);
  float* t2w = (float*)alloc(T_TOK * 2 * 4);
  int*   t2row = (int*)alloc(T_TOK * 2 * 4);
  int*   row2token = (int*)alloc(ROWS_CAP * 4);
  float* roww = (float*)alloc(ROWS_CAP * 4);
  int* ctrs = (int*)alloc(64 * 4);
  int* counts  = ctrs;        // 8
  int* cursors = ctrs + 8;    // 8
  float* psum  = (float*)(ctrs + 16);  // 8
  int* offsets = ctrs + 24;   // 9
  // Y (2 k-slices): 2*9216*1024*4 = 75.5 MB, overlays Wgt+Wut (92.3 MB, dead after gateup)
  float* Y = (float*)Wgt;

  hipMemsetAsync(ctrs, 0, 96, stream);

  conv_x_kernel<<<T_TOK * H_DIM / 4 / 256, 256, 0, stream>>>(x, Xb);
  transpose_all<<<dim3(2112, E_NUM), 256, 0, stream>>>(wg, wu, wd, Wgt, Wut, Wdt);

  router_kernel<<<T_TOK / 16, 256, 0, stream>>>(x, rw, t2i, t2w, counts, psum);
  scan_aux_kernel<<<1, 64, 0, stream>>>(counts, psum, offsets, cursors, out + (size_t)T_TOK * H_DIM);
  assign_kernel<<<T_TOK / 256, 256, 0, stream>>>(t2i, t2w, cursors, row2token, roww, t2row);

  gateup_kernel<<<dim3(TOTAL_MT, F_DIM / 64), 256, 0, stream>>>(Xb, Wgt, Wut, Act, counts, offsets, row2token);
  down_kernel<<<dim3(TOTAL_MT, H_DIM / 128, 2), 256, 0, stream>>>(Act, Wdt, counts, offsets, roww, Y);
  combine_kernel<<<T_TOK, 256, 0, stream>>>(Y, t2row, out);
}

// Round 4
// 609.469 us; speedup vs baseline: 1.0890x; 1.0890x over previous
//
#include <hip/hip_runtime.h>
#include <hip/hip_bf16.h>
#include <stdint.h>

// Problem constants
#define T_TOK 4096   // B*S
#define H_DIM 1024
#define F_DIM 2816
#define E_NUM 8
#define ROWS_CAP 9216   // 8192 + 8*128 padding headroom
#define TOTAL_MT 72     // ROWS_CAP / 128

typedef float  f32x4  __attribute__((ext_vector_type(4)));
typedef __bf16 bf16x8 __attribute__((ext_vector_type(8)));

__device__ __forceinline__ unsigned short f32_bf16(float f) {
  union { float f; unsigned u; } v; v.f = f;
  unsigned r = v.u + 0x7fffu + ((v.u >> 16) & 1u);
  return (unsigned short)(r >> 16);
}

__device__ __forceinline__ void async16(const void* g, void* l) {
  __builtin_amdgcn_global_load_lds(
      (__attribute__((address_space(1))) void*)(g),
      (__attribute__((address_space(3))) void*)(l),
      16, 0, 0);
}

__device__ __forceinline__ f32x4 mfma16(bf16x8 a, bf16x8 b, f32x4 c) {
  return __builtin_amdgcn_mfma_f32_16x16x32_bf16(a, b, c, 0, 0, 0);
}

// ---------------- transpose+convert weights ----------------
// Unified transpose+convert, FLAT grid: exactly 3*704 live 64x64 tiles.
// src [R][C] fp32 -> dst [C][R] bf16.
__global__ __launch_bounds__(256) void transpose_all(const float* __restrict__ wg,
                                                     const float* __restrict__ wu,
                                                     const float* __restrict__ wd,
                                                     unsigned short* __restrict__ Wgt,
                                                     unsigned short* __restrict__ Wut,
                                                     unsigned short* __restrict__ Wdt) {
  int bx = blockIdx.x;            // [0, 2112)
  int mz = bx / 704, local = bx % 704;
  const float* s; unsigned short* d; int R, C, tx;
  size_t mat = (size_t)H_DIM * F_DIM;
  if (mz == 0)      { s = wg; d = Wgt; R = H_DIM; C = F_DIM; tx = 44; }
  else if (mz == 1) { s = wu; d = Wut; R = H_DIM; C = F_DIM; tx = 44; }
  else              { s = wd; d = Wdt; R = F_DIM; C = H_DIM; tx = 16; }
  int c0 = (local % tx) * 64;
  int rg0 = (local / tx) * 64;
  int e = blockIdx.y;
  s += e * mat; d += e * mat;
  int r0 = rg0;

  __shared__ float tile[64 * 65];
  int tid = threadIdx.x;
  int rr = tid >> 4, c4 = tid & 15;
#pragma unroll
  for (int it = 0; it < 4; it++) {
    int r = rr + 16 * it;
    float4 v = *(const float4*)(s + (size_t)(r0 + r) * C + c0 + c4 * 4);
    tile[r * 65 + c4 * 4 + 0] = v.x;
    tile[r * 65 + c4 * 4 + 1] = v.y;
    tile[r * 65 + c4 * 4 + 2] = v.z;
    tile[r * 65 + c4 * 4 + 3] = v.w;
  }
  __syncthreads();
  int cc = tid >> 4, r4 = tid & 15;
#pragma unroll
  for (int it = 0; it < 4; it++) {
    int c = cc + 16 * it;
    ushort4 o;
    o.x = f32_bf16(tile[(r4 * 4 + 0) * 65 + c]);
    o.y = f32_bf16(tile[(r4 * 4 + 1) * 65 + c]);
    o.z = f32_bf16(tile[(r4 * 4 + 2) * 65 + c]);
    o.w = f32_bf16(tile[(r4 * 4 + 3) * 65 + c]);
    *(ushort4*)(d + (size_t)(c0 + c) * R + r0 + r4 * 4) = o;
  }
}

// ---------------- router (fused with x -> bf16 convert) ----------------

__global__ __launch_bounds__(256) void router_kernel(const float* __restrict__ x,
                                                     const float* __restrict__ rw,
                                                     unsigned short* __restrict__ xb,
                                                     int* __restrict__ t2i,
                                                     float* __restrict__ t2w,
                                                     int* __restrict__ counts,
                                                     float* __restrict__ psum) {
  __shared__ float srw[E_NUM * H_DIM];  // 32 KB
  __shared__ float sP[E_NUM];
  __shared__ int sC[E_NUM];
  int tid = threadIdx.x;
  for (int i = tid; i < E_NUM * H_DIM; i += 256) srw[i] = rw[i];
  if (tid < E_NUM) { sP[tid] = 0.f; sC[tid] = 0; }
  // fused x->bf16 for this block's 16 tokens (independent of routing math)
  {
    size_t base = (size_t)blockIdx.x * 16 * H_DIM;
    const float4* src = (const float4*)(x + base);
    ushort4* dst = (ushort4*)(xb + base);
#pragma unroll
    for (int it = 0; it < 16; it++) {
      int i = tid + it * 256;
      float4 v = src[i];
      ushort4 o;
      o.x = f32_bf16(v.x); o.y = f32_bf16(v.y); o.z = f32_bf16(v.z); o.w = f32_bf16(v.w);
      dst[i] = o;
    }
  }
  __syncthreads();
  int w = tid >> 6, lane = tid & 63;
  for (int it = 0; it < 4; ++it) {
    int t = blockIdx.x * 16 + w * 4 + it;
    float acc[E_NUM];
#pragma unroll
    for (int e = 0; e < E_NUM; e++) acc[e] = 0.f;
    const float* xr = x + (size_t)t * H_DIM;
    for (int h = lane; h < H_DIM; h += 64) {
      float xv = xr[h];
#pragma unroll
      for (int e = 0; e < E_NUM; e++) acc[e] += xv * srw[e * H_DIM + h];
    }
#pragma unroll
    for (int e = 0; e < E_NUM; e++) {
      float v = acc[e];
      for (int o = 32; o > 0; o >>= 1) v += __shfl_down(v, o, 64);
      acc[e] = __shfl(v, 0, 64);
    }
    if (lane == 0) {
      float mx = acc[0];
#pragma unroll
      for (int e = 1; e < E_NUM; e++) mx = fmaxf(mx, acc[e]);
      float pr[E_NUM], s = 0.f;
#pragma unroll
      for (int e = 0; e < E_NUM; e++) { pr[e] = __expf(acc[e] - mx); s += pr[e]; }
      float inv = 1.f / s;
#pragma unroll
      for (int e = 0; e < E_NUM; e++) atomicAdd(&sP[e], pr[e] * inv);
      int i0 = 0; float v0 = acc[0];
#pragma unroll
      for (int e = 1; e < E_NUM; e++) if (acc[e] > v0) { v0 = acc[e]; i0 = e; }
      int i1 = -1; float v1 = -3.4e38f;
#pragma unroll
      for (int e = 0; e < E_NUM; e++) if (e != i0 && acc[e] > v1) { v1 = acc[e]; i1 = e; }
      float e1 = __expf(v1 - v0);
      float w0 = 1.f / (1.f + e1);
      t2i[2 * t] = i0; t2i[2 * t + 1] = i1;
      t2w[2 * t] = w0; t2w[2 * t + 1] = e1 * w0;
      atomicAdd(&sC[i0], 1); atomicAdd(&sC[i1], 1);
    }
  }
  __syncthreads();
  if (tid < E_NUM) { atomicAdd(&counts[tid], sC[tid]); atomicAdd(&psum[tid], sP[tid]); }
}

__global__ void scan_aux_kernel(const int* __restrict__ counts, const float* __restrict__ psum,
                                int* __restrict__ offsets, int* __restrict__ cursors,
                                float* __restrict__ aux_out) {
  if (threadIdx.x == 0 && blockIdx.x == 0) {
    int off = 0; float aux = 0.f;
    for (int e = 0; e < E_NUM; e++) {
      offsets[e] = off;
      cursors[e] = off;
      off += (counts[e] + 127) & ~127;
      aux += ((float)counts[e] / 8192.0f) * (psum[e] / 4096.0f);
    }
    offsets[E_NUM] = off;
    *aux_out = 8.0f * aux;
  }
}

__global__ __launch_bounds__(256) void assign_kernel(const int* __restrict__ t2i,
                                                     const float* __restrict__ t2w,
                                                     int* __restrict__ cursors,
                                                     int* __restrict__ row2token,
                                                     float* __restrict__ roww,
                                                     int* __restrict__ t2row) {
  int t = blockIdx.x * 256 + threadIdx.x;
#pragma unroll
  for (int s = 0; s < 2; s++) {
    int e = t2i[2 * t + s];
    int p = atomicAdd(&cursors[e], 1);
    row2token[p] = t;
    roww[p] = t2w[2 * t + s];
    t2row[2 * t + s] = p;
  }
}

// Map a global (padded) row-tile index to its expert via offsets[].
__device__ __forceinline__ int find_expert(const int* __restrict__ offsets, int row0,
                                           int& off_out) {
  int esel = -1, off = 0;
#pragma unroll
  for (int e = 0; e < E_NUM; e++) {
    int lo = offsets[e], hi = offsets[e + 1];
    if (row0 >= lo && row0 < hi) { esel = e; off = lo; }
  }
  off_out = off;
  return esel;
}

// ---------------- fused gate/up GEMM ----------------
// act[row, f] = silu(x@Wg) * (x@Wu), bf16.  BM=128, BN=64, BK=32.
// Round-4: round-0 sync structure (fastest measured: single LDS buffer +
// __syncthreads) + T2 XOR chunk swizzle (conflict-free, verified r2) +
// T1 bijective XCD chunk swizzle: 3168 blocks = 8 XCDs x (44 ntile x 9 m),
// m-fastest within chunk -> per-XCD concurrent working set ~9 A-panels
// (2.3 MB) + ~7 B-tiles (2.7 MB), both L2-resident.
__global__ __launch_bounds__(256) void gateup_kernel(
    const unsigned short* __restrict__ xb,
    const unsigned short* __restrict__ wgt,
    const unsigned short* __restrict__ wut,
    unsigned short* __restrict__ act,
    const int* __restrict__ counts, const int* __restrict__ offsets,
    const int* __restrict__ row2token) {
  // T1 decode: hardware linear (x fastest) -> XCD chunk of 9 m-tiles
  int L = blockIdx.y * 72 + blockIdx.x;   // [0, 3168)
  int c8 = L & 7, pos = L >> 3;           // pos in [0, 396) = 44*9
  int ntile = pos / 9;                    // [0,44)
  int g = c8 * 9 + pos % 9;               // m-tile [0,72)

  int row0 = g * 128;
  int off;
  int e = find_expert(offsets, row0, off);
  if (e < 0) return;
  int cnt = counts[e];
  int rowbase = row0 - off;

  __shared__ __align__(16) unsigned short smA[128 * 32];
  __shared__ __align__(16) unsigned short smG[64 * 32];
  __shared__ __align__(16) unsigned short smU[64 * 32];

  int tid = threadIdx.x;
  int w = tid >> 6, lane = tid & 63;
  int wm = w & 1, wn = w >> 1;  // wave tile 64x32 within 128x64

  // staging: thread tid owns dest (row=tid>>2, chunk=tid&3); source chunk
  // pre-swizzled so that a swizzled ds_read recovers the logical layout.
  int rA0 = tid >> 2, qA0 = tid & 3;
  int qs = qA0 ^ ((rA0 >> 1) & 3);
  int rA1 = rA0 + 64;   // (rA1>>1)&3 == (rA0>>1)&3, same swizzle
  int tok0 = (rowbase + rA0 < cnt) ? row2token[off + rowbase + rA0] : 0;
  int tok1 = (rowbase + rA1 < cnt) ? row2token[off + rowbase + rA1] : 0;
  const unsigned short* gA0 = xb + (size_t)tok0 * H_DIM + qs * 8;
  const unsigned short* gA1 = xb + (size_t)tok1 * H_DIM + qs * 8;
  size_t wb = (size_t)e * F_DIM * H_DIM;
  const unsigned short* gG = wgt + wb + (size_t)(ntile * 64 + rA0) * H_DIM + qs * 8;
  const unsigned short* gU = wut + wb + (size_t)(ntile * 64 + rA0) * H_DIM + qs * 8;
  unsigned short* lA0 = smA + (w * 64) * 8;
  unsigned short* lA1 = smA + (256 + w * 64) * 8;
  unsigned short* lG = smG + (w * 64) * 8;
  unsigned short* lU = smU + (w * 64) * 8;

  f32x4 accg[4][2], accu[4][2];
#pragma unroll
  for (int i = 0; i < 4; i++)
#pragma unroll
    for (int j = 0; j < 2; j++) {
      accg[i][j] = (f32x4){0.f, 0.f, 0.f, 0.f};
      accu[i][j] = (f32x4){0.f, 0.f, 0.f, 0.f};
    }

  int m = lane & 15, quad = lane >> 4;
  // read-side swizzled chunk offset (ushorts); per-thread constant.
  int co = (quad ^ ((m >> 1) & 3)) * 8;

  for (int k0 = 0; k0 < H_DIM; k0 += 32) {
    async16(gA0 + k0, lA0);
    async16(gA1 + k0, lA1);
    async16(gG + k0, lG);
    async16(gU + k0, lU);
    __syncthreads();
    bf16x8 a[4], bg[2], bu[2];
#pragma unroll
    for (int i = 0; i < 4; i++)
      a[i] = *(const bf16x8*)(smA + (wm * 64 + 16 * i + m) * 32 + co);
#pragma unroll
    for (int j = 0; j < 2; j++) {
      bg[j] = *(const bf16x8*)(smG + (wn * 32 + 16 * j + m) * 32 + co);
      bu[j] = *(const bf16x8*)(smU + (wn * 32 + 16 * j + m) * 32 + co);
    }
#pragma unroll
    for (int i = 0; i < 4; i++)
#pragma unroll
      for (int j = 0; j < 2; j++) {
        accg[i][j] = mfma16(a[i], bg[j], accg[i][j]);
        accu[i][j] = mfma16(a[i], bu[j], accu[i][j]);
      }
    __syncthreads();
  }

#pragma unroll
  for (int i = 0; i < 4; i++)
#pragma unroll
    for (int j = 0; j < 2; j++)
#pragma unroll
      for (int r = 0; r < 4; r++) {
        int rt = wm * 64 + 16 * i + quad * 4 + r;
        int ct = wn * 32 + 16 * j + m;
        float g2 = accg[i][j][r], u = accu[i][j][r];
        float sv = g2 / (1.f + __expf(-g2)) * u;
        act[(size_t)(off + rowbase + rt) * F_DIM + ntile * 64 + ct] = f32_bf16(sv);
      }
}

// ---------------- down GEMM, split-k x2 -> Y scratch ----------------
// Y[ks][row, h] = w_row * (act[:, ks*1408:+1408] @ Wd[ks*1408:+1408, :]).
// Round-0 sync structure + T2 swizzle + T1 XCD chunk swizzle
// (1152 = 8 XCDs x (2 ks x 8 ntile x 9 m)).
__global__ __launch_bounds__(256) void down_kernel(
    const unsigned short* __restrict__ act,
    const unsigned short* __restrict__ wdt,   // [E][H][F] k-contig
    const int* __restrict__ counts, const int* __restrict__ offsets,
    const float* __restrict__ roww,
    float* __restrict__ Y) {
  // T1 decode
  int L = (blockIdx.z * 8 + blockIdx.y) * 72 + blockIdx.x;  // [0,1152)
  int c8 = L & 7, pos = L >> 3;          // pos in [0,144) = 16*9
  int g = c8 * 9 + pos % 9;              // m-tile [0,72)
  int rest = pos / 9;                    // [0,16)
  int ntile = rest & 7;                  // [0,8)
  int ks = rest >> 3;                    // [0,2)

  int row0 = g * 128;
  int off;
  int e = find_expert(offsets, row0, off);
  if (e < 0) return;
  int cnt = counts[e];
  int rowbase = row0 - off;
  int kbase = ks * (F_DIM / 2);

  __shared__ __align__(16) unsigned short smA[128 * 32];
  __shared__ __align__(16) unsigned short smB[128 * 32];

  int tid = threadIdx.x;
  int w = tid >> 6, lane = tid & 63;
  int wm = w & 1, wn = w >> 1;  // wave tile 64x64

  int r0 = tid >> 2, q0 = tid & 3;
  int qs = q0 ^ ((r0 >> 1) & 3);
  int r1 = r0 + 64;
  const unsigned short* gA0 = act + (size_t)(off + rowbase + r0) * F_DIM + kbase + qs * 8;
  const unsigned short* gA1 = act + (size_t)(off + rowbase + r1) * F_DIM + kbase + qs * 8;
  size_t wb = (size_t)e * H_DIM * F_DIM;
  const unsigned short* gB0 = wdt + wb + (size_t)(ntile * 128 + r0) * F_DIM + kbase + qs * 8;
  const unsigned short* gB1 = wdt + wb + (size_t)(ntile * 128 + r1) * F_DIM + kbase + qs * 8;
  unsigned short* lA0 = smA + tid * 8;
  unsigned short* lA1 = smA + (tid + 256) * 8;
  unsigned short* lB0 = smB + tid * 8;
  unsigned short* lB1 = smB + (tid + 256) * 8;

  f32x4 acc[4][4];
#pragma unroll
  for (int i = 0; i < 4; i++)
#pragma unroll
    for (int j = 0; j < 4; j++) acc[i][j] = (f32x4){0.f, 0.f, 0.f, 0.f};

  int m = lane & 15, quad = lane >> 4;
  int co = (quad ^ ((m >> 1) & 3)) * 8;

  for (int k0 = 0; k0 < F_DIM / 2; k0 += 32) {
    async16(gA0 + k0, lA0);
    async16(gA1 + k0, lA1);
    async16(gB0 + k0, lB0);
    async16(gB1 + k0, lB1);
    __syncthreads();
    bf16x8 a[4], b[4];
#pragma unroll
    for (int i = 0; i < 4; i++) {
      a[i] = *(const bf16x8*)(smA + (wm * 64 + 16 * i + m) * 32 + co);
      b[i] = *(const bf16x8*)(smB + (wn * 64 + 16 * i + m) * 32 + co);
    }
#pragma unroll
    for (int i = 0; i < 4; i++)
#pragma unroll
      for (int j = 0; j < 4; j++) acc[i][j] = mfma16(a[i], b[j], acc[i][j]);
    __syncthreads();
  }

  float* Yk = Y + (size_t)ks * ROWS_CAP * H_DIM;
#pragma unroll
  for (int i = 0; i < 4; i++)
#pragma unroll
    for (int r = 0; r < 4; r++) {
      int rt = wm * 64 + 16 * i + quad * 4 + r;
      int lrow = rowbase + rt;
      if (lrow < cnt) {
        float cw = roww[off + lrow];
#pragma unroll
        for (int j = 0; j < 4; j++) {
          int h = ntile * 128 + wn * 64 + 16 * j + m;
          Yk[(size_t)(off + lrow) * H_DIM + h] = cw * acc[i][j][r];
        }
      }
    }
}

// out[t] = sum over 2 rows x 2 k-slices of Y
__global__ __launch_bounds__(256) void combine_kernel(const float* __restrict__ Y,
                                                      const int* __restrict__ t2row,
                                                      float* __restrict__ out) {
  int t = blockIdx.x, hc = threadIdx.x;
  int r0 = t2row[2 * t], r1 = t2row[2 * t + 1];
  const float* Y1 = Y + (size_t)ROWS_CAP * H_DIM;
  float4 a = ((const float4*)(Y  + (size_t)r0 * H_DIM))[hc];
  float4 b = ((const float4*)(Y  + (size_t)r1 * H_DIM))[hc];
  float4 c = ((const float4*)(Y1 + (size_t)r0 * H_DIM))[hc];
  float4 d = ((const float4*)(Y1 + (size_t)r1 * H_DIM))[hc];
  float4 o;
  o.x = (a.x + b.x) + (c.x + d.x);
  o.y = (a.y + b.y) + (c.y + d.y);
  o.z = (a.z + b.z) + (c.z + d.z);
  o.w = (a.w + b.w) + (c.w + d.w);
  ((float4*)(out + (size_t)t * H_DIM))[hc] = o;
}

// ---------------- host ----------------

extern "C" void kernel_launch(void* const* d_in, const int* in_sizes, int n_in,
                              void* d_out, int out_size, void* d_ws, size_t ws_size,
                              hipStream_t stream) {
  const float* x  = (const float*)d_in[0];
  const float* rw = (const float*)d_in[1];
  const float* wg = (const float*)d_in[2];
  const float* wu = (const float*)d_in[3];
  const float* wd = (const float*)d_in[4];
  float* out = (float*)d_out;

  char* ws = (char*)d_ws;
  size_t p = 0;
  auto alloc = [&](size_t bytes) {
    char* r = ws + p;
    p = (p + bytes + 255) & ~(size_t)255;
    return r;
  };
  unsigned short* Xb  = (unsigned short*)alloc((size_t)T_TOK * H_DIM * 2);
  unsigned short* Wgt = (unsigned short*)alloc((size_t)E_NUM * F_DIM * H_DIM * 2);
  unsigned short* Wut = (unsigned short*)alloc((size_t)E_NUM * F_DIM * H_DIM * 2);
  unsigned short* Wdt = (unsigned short*)alloc((size_t)E_NUM * H_DIM * F_DIM * 2);
  unsigned short* Act = (unsigned short*)alloc((size_t)ROWS_CAP * F_DIM * 2);
  int*   t2i = (int*)alloc(T_TOK * 2 * 4);
  float* t2w = (float*)alloc(T_TOK * 2 * 4);
  int*   t2row = (int*)alloc(T_TOK * 2 * 4);
  int*   row2token = (int*)alloc(ROWS_CAP * 4);
  float* roww = (float*)alloc(ROWS_CAP * 4);
  int* ctrs = (int*)alloc(64 * 4);
  int* counts  = ctrs;        // 8
  int* cursors = ctrs + 8;    // 8
  float* psum  = (float*)(ctrs + 16);  // 8
  int* offsets = ctrs + 24;   // 9
  // Y (2 k-slices): 2*9216*1024*4 = 75.5 MB, overlays Wgt+Wut (92.3 MB, dead after gateup)
  float* Y = (float*)Wgt;

  hipMemsetAsync(ctrs, 0, 96, stream);

  transpose_all<<<dim3(2112, E_NUM), 256, 0, stream>>>(wg, wu, wd, Wgt, Wut, Wdt);

  router_kernel<<<T_TOK / 16, 256, 0, stream>>>(x, rw, Xb, t2i, t2w, counts, psum);
  scan_aux_kernel<<<1, 64, 0, stream>>>(counts, psum, offsets, cursors, out + (size_t)T_TOK * H_DIM);
  assign_kernel<<<T_TOK / 256, 256, 0, stream>>>(t2i, t2w, cursors, row2token, roww, t2row);

  gateup_kernel<<<dim3(TOTAL_MT, F_DIM / 64), 256, 0, stream>>>(Xb, Wgt, Wut, Act, counts, offsets, row2token);
  down_kernel<<<dim3(TOTAL_MT, H_DIM / 128, 2), 256, 0, stream>>>(Act, Wdt, counts, offsets, roww, Y);
  combine_kernel<<<T_TOK, 256, 0, stream>>>(Y, t2row, out);
}